// Round 7
// baseline (473.680 us; speedup 1.0000x reference)
//
#include <hip/hip_runtime.h>

#define BM 128
#define BN 128
#define BK 32

typedef unsigned short u16;
typedef unsigned int u32;
typedef __attribute__((ext_vector_type(8))) short short8;
typedef __attribute__((ext_vector_type(4))) float floatx4;

__device__ __forceinline__ u16 f2bf(float f) {
  u32 u = __float_as_uint(f);
  return (u16)((u + 0x7FFFu + ((u >> 16) & 1u)) >> 16);  // RNE
}

__device__ __forceinline__ float bf2f(u16 b) {
  return __uint_as_float(((u32)b) << 16);
}

__device__ __forceinline__ void gload16(const void* g, void* l) {
  __builtin_amdgcn_global_load_lds((const __attribute__((address_space(1))) void*)g,
                                   (__attribute__((address_space(3))) void*)l, 16, 0, 0);
}

// ---------------------------------------------------------------------------
// Deep-pipelined 256x256 GEMM. C = scale * A[M,K] @ B'[N,K]^T + bias.
// bf16 in/out (fp32 accum), 512 thr = 8 waves (2M x 4N), per-wave C 128x64.
// 4-deep LDS ring (4 x 32KB); tile T+3 staged while T computes; gate is
// counted vmcnt(8) + 1 barrier per tile (never vmcnt(0) in steady state).
// vmcnt ledger (4 loads/tile/thread): at end of tile T, tile T+1 must be
// resident; younger loads = T+2 + T+3 stages = 8 -> vmcnt(8);
// T==NT-3 -> vmcnt(4); T==NT-2 -> vmcnt(0). Requires NT >= 4.
// CAUSAL: skip tiles fully above diagonal (diag tiles computed fully; the
// above-diagonal garbage is never read downstream — softmax masks by index).
// ---------------------------------------------------------------------------
template<int BIAS_MODE, bool CAUSAL, int SWZ>
__global__ __launch_bounds__(512, 2)
void gemm256(const u16* __restrict__ A, int lda, long strideA,
             const u16* __restrict__ B, int ldb, long strideB,
             u16* __restrict__ C, int ldc, long strideC,
             const float* __restrict__ bias, float scale, int K)
{
  int bx = blockIdx.x, by = blockIdx.y;
  if (SWZ == 1) {
    const int c = gridDim.x >> 3;
    bx = (bx & 7) * c + (bx >> 3);
  } else if (SWZ == 2) {
    const u32 gx = gridDim.x;
    const u32 flat = (u32)by * gx + (u32)bx;
    const u32 j = flat & 7u, w = flat >> 3;
    const u32 rpx = gridDim.y >> 3;
    by = (int)(j * rpx + w / gx);
    bx = (int)(w % gx);
  }
  const int rb = by * 256, cb = bx * 256;
  if (CAUSAL && cb > rb + 255) return;

  A += (long)blockIdx.z * strideA;
  B += (long)blockIdx.z * strideB;
  const long coff = (long)blockIdx.z * strideC;

  __shared__ __align__(16) char lds[131072];  // 4 bufs x (A 16KB | B 16KB)

  const int t = threadIdx.x;           // 0..511
  const int lane = t & 63, wid = t >> 6;
  const int wr = wid >> 2, wc = wid & 3;

  floatx4 acc[8][4];
#pragma unroll
  for (int i = 0; i < 8; ++i)
#pragma unroll
    for (int j = 0; j < 4; ++j) acc[i][j] = (floatx4)(0.0f);

  // Staging: thread t covers row sr=t>>2 (and sr+128), physical chunk t&3,
  // logical chunk XOR-swizzled: l = (t&3) ^ ((sr>>1)&3).
  const int sr = t >> 2;
  const int sl = (t & 3) ^ ((sr >> 1) & 3);
  const u16* Ag0 = A + (long)(rb + sr) * lda + sl * 8;
  const u16* Ag1 = A + (long)(rb + sr + 128) * lda + sl * 8;
  const u16* Bg0 = B + (long)(cb + sr) * ldb + sl * 8;
  const u16* Bg1 = B + (long)(cb + sr + 128) * ldb + sl * 8;

#define STAGE_A(T) { const long ko_ = (long)(T) * 32;                          \
    char* d_ = lds + (((T) & 3) << 15) + (wid << 10);                          \
    gload16(Ag0 + ko_, d_); gload16(Ag1 + ko_, d_ + 8192); }
#define STAGE_B(T) { const long ko_ = (long)(T) * 32;                          \
    char* d_ = lds + (((T) & 3) << 15) + 16384 + (wid << 10);                  \
    gload16(Bg0 + ko_, d_); gload16(Bg1 + ko_, d_ + 8192); }

  const int g = lane >> 4;
  int aoff[8], boff[4];
  const int arow = wr * 128 + (lane & 15);
  const int brow = wc * 64 + (lane & 15);
#pragma unroll
  for (int i = 0; i < 8; ++i) {
    const int ra = arow + i * 16;
    aoff[i] = ra * 64 + ((g ^ ((ra >> 1) & 3)) * 16);
  }
#pragma unroll
  for (int j = 0; j < 4; ++j) {
    const int rbq = brow + j * 16;
    boff[j] = rbq * 64 + ((g ^ ((rbq >> 1) & 3)) * 16);
  }

  const int NT = K / 32;  // >= 4

  STAGE_A(0); STAGE_B(0);
  STAGE_A(1); STAGE_B(1);
  STAGE_A(2); STAGE_B(2);
  asm volatile("s_waitcnt vmcnt(8)" ::: "memory");
  __builtin_amdgcn_s_barrier();
  asm volatile("" ::: "memory");

  for (int T = 0; T < NT; ++T) {
    const char* bufA = lds + ((T & 3) << 15);
    const char* bufB = bufA + 16384;

    if (T + 3 < NT) STAGE_A(T + 3);
    short8 a0[4], bfr[4];
#pragma unroll
    for (int i = 0; i < 4; ++i) a0[i] = *(const short8*)(bufA + aoff[i]);
#pragma unroll
    for (int j = 0; j < 4; ++j) bfr[j] = *(const short8*)(bufB + boff[j]);
    __builtin_amdgcn_s_setprio(1);
#pragma unroll
    for (int mi = 0; mi < 4; ++mi)
#pragma unroll
      for (int nj = 0; nj < 4; ++nj)
        acc[mi][nj] = __builtin_amdgcn_mfma_f32_16x16x32_bf16(a0[mi], bfr[nj], acc[mi][nj], 0, 0, 0);
    __builtin_amdgcn_s_setprio(0);

    if (T + 3 < NT) STAGE_B(T + 3);
    short8 a1[4];
#pragma unroll
    for (int i = 0; i < 4; ++i) a1[i] = *(const short8*)(bufA + aoff[4 + i]);
    __builtin_amdgcn_s_setprio(1);
#pragma unroll
    for (int mi = 0; mi < 4; ++mi)
#pragma unroll
      for (int nj = 0; nj < 4; ++nj)
        acc[4 + mi][nj] = __builtin_amdgcn_mfma_f32_16x16x32_bf16(a1[mi], bfr[nj], acc[4 + mi][nj], 0, 0, 0);
    __builtin_amdgcn_s_setprio(0);

    asm volatile("" ::: "memory");
    if (T < NT - 3) {
      asm volatile("s_waitcnt vmcnt(8)" ::: "memory");
      __builtin_amdgcn_s_barrier();
    } else if (T == NT - 3) {
      asm volatile("s_waitcnt vmcnt(4)" ::: "memory");
      __builtin_amdgcn_s_barrier();
    } else if (T == NT - 2) {
      asm volatile("s_waitcnt vmcnt(0)" ::: "memory");
      __builtin_amdgcn_s_barrier();
    }
    asm volatile("" ::: "memory");
  }
#undef STAGE_A
#undef STAGE_B

#pragma unroll
  for (int mi = 0; mi < 8; ++mi) {
    const int r0 = rb + wr * 128 + mi * 16 + (lane >> 4) * 4;
#pragma unroll
    for (int nj = 0; nj < 4; ++nj) {
      const int c = cb + wc * 64 + nj * 16 + (lane & 15);
      float bc = 0.0f;
      if (BIAS_MODE == 1) bc = bias[c];
#pragma unroll
      for (int e = 0; e < 4; ++e) {
        const int r = r0 + e;
        float val = acc[mi][nj][e] * scale + bc;
        if (BIAS_MODE == 2) val += bias[r];
        C[coff + (long)r * ldc + c] = f2bf(val);
      }
    }
  }
}

// ---------------------------------------------------------------------------
// 128x128 m97-style GEMM (PV). SPLITK=2: blockIdx.y = tile*2+s; split s covers
// K in [s*1024, min(kend, s*1024+1024)); both splits atomicAdd into zeroed C.
// ---------------------------------------------------------------------------
template<int BIAS_MODE, bool OUT_BF16, bool CAUSAL, bool KLIMIT, int SWZ, int SPLITK>
__global__ __launch_bounds__(256)
void gemm_nt(const u16* __restrict__ A, int lda, long strideA,
             const u16* __restrict__ B, int ldb, long strideB,
             void* __restrict__ Cv, int ldc, long strideC,
             const float* __restrict__ bias, float scale,
             int M, int N, int K)
{
  int bx = blockIdx.x;
  int by = blockIdx.y;
  int ks = 0;
  if (SPLITK > 1) { ks = by % SPLITK; by /= SPLITK; }
  if (SWZ == 1) {
    const int c = gridDim.x >> 3;
    bx = (bx & 7) * c + (bx >> 3);
  } else if (SWZ == 2) {
    const u32 gx = gridDim.x;
    const u32 flat = (u32)by * gx + (u32)bx;
    const u32 j = flat & 7u;
    const u32 w = flat >> 3;
    const u32 rpx = gridDim.y >> 3;
    by = (int)(j * rpx + w / gx);
    bx = (int)(w % gx);
  } else if (SWZ == 3) {
    by = (gridDim.y / SPLITK) - 1 - by;
  }
  const int rb = by * BM;
  const int cb = bx * BN;
  if (CAUSAL && cb > rb + (BM - 1)) return;

  int kend = K;
  if (KLIMIT) kend = (rb + BM < K) ? (rb + BM) : K;
  int klo = 0, khi = kend;
  if (SPLITK > 1) {
    klo = ks * 1024;
    khi = (kend < klo + 1024) ? kend : (klo + 1024);
    if (klo >= khi) return;
  }

  A += (long)blockIdx.z * strideA;
  B += (long)blockIdx.z * strideB;
  const long coff = (long)blockIdx.z * strideC;

  __shared__ u16 As[BM * BK];
  __shared__ u16 Bs[BN * BK];

  const int t = threadIdx.x;
  const int lane = t & 63;
  const int wid = t >> 6;
  const int wr = wid >> 1, wc = wid & 1;

  floatx4 acc[4][4];
#pragma unroll
  for (int i = 0; i < 4; ++i)
#pragma unroll
    for (int j = 0; j < 4; ++j) acc[i][j] = (floatx4)(0.0f);

  const int srow = t >> 2;
  const int schunk = (t & 3) ^ ((srow >> 1) & 3);
  const u16* Ag0 = A + (long)(rb + srow) * lda + schunk * 8;
  const u16* Ag1 = A + (long)(rb + srow + 64) * lda + schunk * 8;
  const u16* Bg0 = B + (long)(cb + srow) * ldb + schunk * 8;
  const u16* Bg1 = B + (long)(cb + srow + 64) * ldb + schunk * 8;
  char* AsW = (char*)As + wid * 1024;
  char* BsW = (char*)Bs + wid * 1024;

  const int arow = wr * 64 + (lane & 15);
  const int brow = wc * 64 + (lane & 15);
  const int rchunk = lane >> 4;
  int aoff[4], boff[4];
#pragma unroll
  for (int i = 0; i < 4; ++i) {
    const int ra = arow + i * 16;
    aoff[i] = ra * 64 + ((rchunk ^ ((ra >> 1) & 3)) * 16);
    const int rbq = brow + i * 16;
    boff[i] = rbq * 64 + ((rchunk ^ ((rbq >> 1) & 3)) * 16);
  }

  for (int kt = klo / BK; kt < khi / BK; ++kt) {
    const long ko = (long)kt * BK;
    gload16(Ag0 + ko, AsW);
    gload16(Ag1 + ko, AsW + 4096);
    gload16(Bg0 + ko, BsW);
    gload16(Bg1 + ko, BsW + 4096);
    __syncthreads();
    short8 af[4], bfr[4];
#pragma unroll
    for (int i = 0; i < 4; ++i) {
      af[i]  = *(const short8*)((const char*)As + aoff[i]);
      bfr[i] = *(const short8*)((const char*)Bs + boff[i]);
    }
#pragma unroll
    for (int mi = 0; mi < 4; ++mi)
#pragma unroll
      for (int nj = 0; nj < 4; ++nj)
        acc[mi][nj] = __builtin_amdgcn_mfma_f32_16x16x32_bf16(af[mi], bfr[nj], acc[mi][nj], 0, 0, 0);
    __syncthreads();
  }

#pragma unroll
  for (int mi = 0; mi < 4; ++mi) {
    const int r0 = rb + wr * 64 + mi * 16 + (lane >> 4) * 4;
#pragma unroll
    for (int nj = 0; nj < 4; ++nj) {
      const int c = cb + wc * 64 + nj * 16 + (lane & 15);
      float bc = 0.0f;
      if (BIAS_MODE == 1) bc = bias[c];
#pragma unroll
      for (int e = 0; e < 4; ++e) {
        const int r = r0 + e;
        float val = acc[mi][nj][e] * scale + bc;
        if (BIAS_MODE == 2) val += bias[r];
        const long idx = coff + (long)r * ldc + c;
        if (SPLITK > 1)      atomicAdd((float*)Cv + idx, val);
        else if (OUT_BF16)   ((u16*)Cv)[idx] = f2bf(val);
        else                 ((float*)Cv)[idx] = val;
      }
    }
  }
}

// In-place causal row softmax over bf16 scores (reads only j<=i chunks).
__global__ __launch_bounds__(256)
void softmax_causal_bf16(u16* __restrict__ Pp, int n, long stride)
{
  const int i = blockIdx.x;
  u16* row = Pp + (long)blockIdx.y * stride + (long)i * n;
  const int t = threadIdx.x;
  const int lane = t & 63, wid = t >> 6;
  const int jb = t * 8;

  float v[8];
  const bool any = (jb <= i);
  if (any) {
    short8 sv = *(const short8*)(row + jb);
#pragma unroll
    for (int e = 0; e < 8; ++e) v[e] = bf2f((u16)sv[e]);
  } else {
#pragma unroll
    for (int e = 0; e < 8; ++e) v[e] = 0.0f;
  }

  float mx = -3.0e38f;
#pragma unroll
  for (int e = 0; e < 8; ++e) if (any && jb + e <= i) mx = fmaxf(mx, v[e]);
#pragma unroll
  for (int off = 32; off > 0; off >>= 1) mx = fmaxf(mx, __shfl_xor(mx, off));
  __shared__ float red[8];
  if (lane == 0) red[wid] = mx;
  __syncthreads();
  mx = fmaxf(fmaxf(red[0], red[1]), fmaxf(red[2], red[3]));

  float s = 0.0f;
#pragma unroll
  for (int e = 0; e < 8; ++e) {
    float p = (any && jb + e <= i) ? __expf(v[e] - mx) : 0.0f;
    v[e] = p; s += p;
  }
#pragma unroll
  for (int off = 32; off > 0; off >>= 1) s += __shfl_xor(s, off);
  if (lane == 0) red[4 + wid] = s;
  __syncthreads();
  s = red[4] + red[5] + red[6] + red[7];
  const float inv = 1.0f / s;

  short8 o;
#pragma unroll
  for (int e = 0; e < 8; ++e) o[e] = (short)f2bf(v[e] * inv);
  *(short8*)(row + jb) = o;
}

__global__ __launch_bounds__(256)
void transpose_conv(const float* __restrict__ W, u16* __restrict__ WT, int dim)
{
  __shared__ float tile[32][33];
  const int tx = threadIdx.x & 31;
  const int ty = threadIdx.x >> 5;
  const int c0 = blockIdx.x * 32;
  const int r0 = blockIdx.y * 32;
#pragma unroll
  for (int i = 0; i < 4; ++i)
    tile[ty + 8 * i][tx] = W[(long)(r0 + ty + 8 * i) * dim + c0 + tx];
  __syncthreads();
#pragma unroll
  for (int i = 0; i < 4; ++i)
    WT[(long)(c0 + ty + 8 * i) * dim + r0 + tx] = f2bf(tile[tx][ty + 8 * i]);
}

__global__ __launch_bounds__(256)
void conv_bf16(const float* __restrict__ X, u16* __restrict__ Xb, long n8)
{
  const long i = (long)blockIdx.x * 256 + threadIdx.x;
  if (i >= n8) return;
  const float4* s = (const float4*)X + i * 2;
  float4 a = s[0], b = s[1];
  short8 o;
  o[0] = (short)f2bf(a.x); o[1] = (short)f2bf(a.y);
  o[2] = (short)f2bf(a.z); o[3] = (short)f2bf(a.w);
  o[4] = (short)f2bf(b.x); o[5] = (short)f2bf(b.y);
  o[6] = (short)f2bf(b.z); o[7] = (short)f2bf(b.w);
  ((short8*)Xb)[i] = o;
}

__global__ __launch_bounds__(256)
void pack_bias2(const float* __restrict__ b0, const float* __restrict__ b1,
                float* __restrict__ dst, int n)
{
  const int i = blockIdx.x * 256 + threadIdx.x;
  if (i < n) dst[i] = b0[i];
  else if (i < 2 * n) dst[i] = b1[i - n];
}

// Zero d_out (poisoned 0xAA by harness) so split-K PV can atomicAdd into it.
__global__ __launch_bounds__(256)
void zero_f4(float4* __restrict__ p, long n4)
{
  const long stride = (long)gridDim.x * 256;
  for (long i = (long)blockIdx.x * 256 + threadIdx.x; i < n4; i += stride)
    p[i] = make_float4(0.f, 0.f, 0.f, 0.f);
}

extern "C" void kernel_launch(void* const* d_in, const int* in_sizes, int n_in,
                              void* d_out, int out_size, void* d_ws, size_t ws_size,
                              hipStream_t stream)
{
  const int Bb = 8, S = 2048, Dd = 1024, Od = 1024;
  const int M = Bb * S;  // 16384

  const float* x  = (const float*)d_in[0];
  const float* Wq = (const float*)d_in[1];
  const float* bq = (const float*)d_in[2];
  const float* Wk = (const float*)d_in[3];
  const float* bk = (const float*)d_in[4];
  const float* Wv = (const float*)d_in[5];
  const float* bv = (const float*)d_in[6];
  float* out = (float*)d_out;

  char* ws = (char*)d_ws;
  u16* xb   = (u16*)(ws);                 // x bf16 [16384][1024], 32MB (dead after projections)
  u16* qk   = (u16*)(ws + 33554432L);     // fused q|k [16384][2048] bf16, 64MB
  u16* vT   = (u16*)(ws + 100663296L);    // v^T [1024][16384] bf16, 32MB
  u16* WqkT = (u16*)(ws + 134217728L);    // packed [2048][1024] bf16, 4MB
  u16* WvT  = (u16*)(ws + 138412032L);    // [1024][1024] bf16, 2MB
  float* bqk = (float*)(ws + 140509184L); // packed [2048] fp32, 8KB
  const size_t attn_base = 140517376UL;

  zero_f4<<<dim3(2048), dim3(256), 0, stream>>>((float4*)out, (long)out_size / 4);
  conv_bf16<<<dim3(8192), dim3(256), 0, stream>>>(x, xb, (long)M * Dd / 8);
  transpose_conv<<<dim3(32, 32), dim3(256), 0, stream>>>(Wq, WqkT, Dd);
  transpose_conv<<<dim3(32, 32), dim3(256), 0, stream>>>(Wk, WqkT + (long)Od * Dd, Dd);
  transpose_conv<<<dim3(32, 32), dim3(256), 0, stream>>>(Wv, WvT, Dd);
  pack_bias2<<<dim3(8), dim3(256), 0, stream>>>(bq, bk, bqk, Od);

  // Fused q|k projection (deep-pipelined 256^2): C[16384][2048].
  gemm256<1, false, 2><<<dim3(2 * Od / 256, M / 256), dim3(512), 0, stream>>>(
      xb, Dd, 0L, WqkT, Dd, 0L, qk, 2 * Od, 0L, bqk, 1.0f, Dd);
  // v^T (deep-pipelined 256^2): vT[d][m] = WvT[d][:] . xb[m][:] + bv[d].
  gemm256<2, false, 1><<<dim3(M / 256, Od / 256), dim3(512), 0, stream>>>(
      WvT, Dd, 0L, xb, Dd, 0L, vT, M, 0L, bv, 1.0f, Dd);

  const u16* qb = qk;            // lda = 2048
  const u16* kb = qk + Od;       // lda = 2048
  const int ldqk = 2 * Od;
  const long strideQK = (long)S * ldqk;
  const long sS = (long)S * S;

  // Score buffer: tail region if 8 batches fit; else reuse dead xb (4 fit).
  u16* scores;
  int g;
  if (ws_size >= attn_base + 8UL * (size_t)sS * sizeof(u16)) {
    scores = (u16*)(ws + attn_base);
    g = 8;
  } else {
    scores = xb;
    g = 4;
  }

  dim3 blk(256);
  const float sc = 0.03125f;  // 1/sqrt(1024)
  for (int b0 = 0; b0 < Bb; b0 += g) {
    const int gz = (b0 + g <= Bb) ? g : (Bb - b0);
    // scores (deep-pipelined 256^2, causal tile-skip, bf16 out)
    gemm256<0, true, 0><<<dim3(S / 256, S / 256, gz), dim3(512), 0, stream>>>(
        qb + (long)b0 * strideQK, ldqk, strideQK,
        kb + (long)b0 * strideQK, ldqk, strideQK,
        scores, S, sS, nullptr, sc, Od);
    // in-place softmax -> bf16 probs (zeros above diagonal)
    softmax_causal_bf16<<<dim3(S, gz), blk, 0, stream>>>(scores, S, sS);
    // out = probs @ v: 128^2, causal K-limit, split-K=2, atomic into zeroed out
    gemm_nt<0, false, false, true, 3, 2><<<dim3(Od / BN, (S / BM) * 2, gz), blk, 0, stream>>>(
        scores, S, sS, vT + (long)b0 * S, M, (long)S,
        out + (long)b0 * S * Od, Od, (long)S * Od, nullptr, 1.0f, S, Od, S);
  }
}

// Round 8
// 407.167 us; speedup vs baseline: 1.1634x; 1.1634x over previous
//
#include <hip/hip_runtime.h>

typedef unsigned short u16;
typedef unsigned int u32;
typedef __attribute__((ext_vector_type(8))) short short8;
typedef __attribute__((ext_vector_type(4))) float floatx4;

__device__ __forceinline__ u16 f2bf(float f) {
  u32 u = __float_as_uint(f);
  return (u16)((u + 0x7FFFu + ((u >> 16) & 1u)) >> 16);  // RNE
}

__device__ __forceinline__ float bf2f(u16 b) {
  return __uint_as_float(((u32)b) << 16);
}

__device__ __forceinline__ void gload16(const void* g, void* l) {
  __builtin_amdgcn_global_load_lds((const __attribute__((address_space(1))) void*)g,
                                   (__attribute__((address_space(3))) void*)l, 16, 0, 0);
}

// ---------------------------------------------------------------------------
// Deep-pipelined 256x256 GEMM. C = scale * A[M,K] @ B'[N,K]^T + bias.
// bf16 in (fp32 accum), out bf16 or fp32. 512 thr = 8 waves (2M x 4N),
// per-wave C 128x64. 4-deep LDS ring (4 x 32KB); tile T+3 staged while T
// computes; gate = counted vmcnt(8) + 1 barrier per tile (never vmcnt(0) in
// steady state). vmcnt ledger (4 loads/tile/thread): at end of tile T, tile
// T+1 must be resident; younger loads = stages of T+2,T+3 = 8 -> vmcnt(8);
// T==NT-3 -> vmcnt(4); T==NT-2 -> vmcnt(0). Requires NT >= 4.
// CAUSAL: skip tiles fully above diagonal (diag-tile garbage never read
// downstream - softmax masks by index). KLIMIT: K-extent = min(rb+256, K)
// (PV: probs row tile rb has zero cols beyond rb+255).
// ---------------------------------------------------------------------------
template<int BIAS_MODE, bool OUT_BF16, bool CAUSAL, bool KLIMIT, int SWZ>
__global__ __launch_bounds__(512, 2)
void gemm256(const u16* __restrict__ A, int lda, long strideA,
             const u16* __restrict__ B, int ldb, long strideB,
             void* __restrict__ Cv, int ldc, long strideC,
             const float* __restrict__ bias, float scale, int K)
{
  int bx = blockIdx.x, by = blockIdx.y;
  if (SWZ == 1) {
    const int c = gridDim.x >> 3;
    bx = (bx & 7) * c + (bx >> 3);
  } else if (SWZ == 2) {
    const u32 gx = gridDim.x;
    const u32 flat = (u32)by * gx + (u32)bx;
    const u32 j = flat & 7u, w = flat >> 3;
    const u32 rpx = gridDim.y >> 3;
    by = (int)(j * rpx + w / gx);
    bx = (int)(w % gx);
  }
  const int rb = by * 256, cb = bx * 256;
  if (CAUSAL && cb > rb + 255) return;

  A += (long)blockIdx.z * strideA;
  B += (long)blockIdx.z * strideB;
  const long coff = (long)blockIdx.z * strideC;

  __shared__ __align__(16) char lds[131072];  // 4 bufs x (A 16KB | B 16KB)

  const int t = threadIdx.x;           // 0..511
  const int lane = t & 63, wid = t >> 6;
  const int wr = wid >> 2, wc = wid & 3;

  floatx4 acc[8][4];
#pragma unroll
  for (int i = 0; i < 8; ++i)
#pragma unroll
    for (int j = 0; j < 4; ++j) acc[i][j] = (floatx4)(0.0f);

  // Staging: thread t covers row sr=t>>2 (and sr+128), physical chunk t&3,
  // logical chunk XOR-swizzled: l = (t&3) ^ ((sr>>1)&3).
  const int sr = t >> 2;
  const int sl = (t & 3) ^ ((sr >> 1) & 3);
  const u16* Ag0 = A + (long)(rb + sr) * lda + sl * 8;
  const u16* Ag1 = A + (long)(rb + sr + 128) * lda + sl * 8;
  const u16* Bg0 = B + (long)(cb + sr) * ldb + sl * 8;
  const u16* Bg1 = B + (long)(cb + sr + 128) * ldb + sl * 8;

#define STAGE_A(T) { const long ko_ = (long)(T) * 32;                          \
    char* d_ = lds + (((T) & 3) << 15) + (wid << 10);                          \
    gload16(Ag0 + ko_, d_); gload16(Ag1 + ko_, d_ + 8192); }
#define STAGE_B(T) { const long ko_ = (long)(T) * 32;                          \
    char* d_ = lds + (((T) & 3) << 15) + 16384 + (wid << 10);                  \
    gload16(Bg0 + ko_, d_); gload16(Bg1 + ko_, d_ + 8192); }

  const int g = lane >> 4;
  int aoff[8], boff[4];
  const int arow = wr * 128 + (lane & 15);
  const int brow = wc * 64 + (lane & 15);
#pragma unroll
  for (int i = 0; i < 8; ++i) {
    const int ra = arow + i * 16;
    aoff[i] = ra * 64 + ((g ^ ((ra >> 1) & 3)) * 16);
  }
#pragma unroll
  for (int j = 0; j < 4; ++j) {
    const int rbq = brow + j * 16;
    boff[j] = rbq * 64 + ((g ^ ((rbq >> 1) & 3)) * 16);
  }

  int kend = K;
  if (KLIMIT) kend = (rb + 256 < K) ? (rb + 256) : K;
  const int NT = kend / 32;  // >= 4 whenever K >= 128

  STAGE_A(0); STAGE_B(0);
  STAGE_A(1); STAGE_B(1);
  STAGE_A(2); STAGE_B(2);
  asm volatile("s_waitcnt vmcnt(8)" ::: "memory");
  __builtin_amdgcn_s_barrier();
  asm volatile("" ::: "memory");

  for (int T = 0; T < NT; ++T) {
    const char* bufA = lds + ((T & 3) << 15);
    const char* bufB = bufA + 16384;

    if (T + 3 < NT) STAGE_A(T + 3);
    short8 a0[4], bfr[4];
#pragma unroll
    for (int i = 0; i < 4; ++i) a0[i] = *(const short8*)(bufA + aoff[i]);
#pragma unroll
    for (int j = 0; j < 4; ++j) bfr[j] = *(const short8*)(bufB + boff[j]);
    __builtin_amdgcn_s_setprio(1);
#pragma unroll
    for (int mi = 0; mi < 4; ++mi)
#pragma unroll
      for (int nj = 0; nj < 4; ++nj)
        acc[mi][nj] = __builtin_amdgcn_mfma_f32_16x16x32_bf16(a0[mi], bfr[nj], acc[mi][nj], 0, 0, 0);
    __builtin_amdgcn_s_setprio(0);

    if (T + 3 < NT) STAGE_B(T + 3);
    short8 a1[4];
#pragma unroll
    for (int i = 0; i < 4; ++i) a1[i] = *(const short8*)(bufA + aoff[4 + i]);
    __builtin_amdgcn_s_setprio(1);
#pragma unroll
    for (int mi = 0; mi < 4; ++mi)
#pragma unroll
      for (int nj = 0; nj < 4; ++nj)
        acc[4 + mi][nj] = __builtin_amdgcn_mfma_f32_16x16x32_bf16(a1[mi], bfr[nj], acc[4 + mi][nj], 0, 0, 0);
    __builtin_amdgcn_s_setprio(0);

    asm volatile("" ::: "memory");
    if (T < NT - 3) {
      asm volatile("s_waitcnt vmcnt(8)" ::: "memory");
      __builtin_amdgcn_s_barrier();
    } else if (T == NT - 3) {
      asm volatile("s_waitcnt vmcnt(4)" ::: "memory");
      __builtin_amdgcn_s_barrier();
    } else if (T == NT - 2) {
      asm volatile("s_waitcnt vmcnt(0)" ::: "memory");
      __builtin_amdgcn_s_barrier();
    }
    asm volatile("" ::: "memory");
  }
#undef STAGE_A
#undef STAGE_B

#pragma unroll
  for (int mi = 0; mi < 8; ++mi) {
    const int r0 = rb + wr * 128 + mi * 16 + (lane >> 4) * 4;
#pragma unroll
    for (int nj = 0; nj < 4; ++nj) {
      const int c = cb + wc * 64 + nj * 16 + (lane & 15);
      float bc = 0.0f;
      if (BIAS_MODE == 1) bc = bias[c];
#pragma unroll
      for (int e = 0; e < 4; ++e) {
        const int r = r0 + e;
        float val = acc[mi][nj][e] * scale + bc;
        if (BIAS_MODE == 2) val += bias[r];
        const long idx = coff + (long)r * ldc + c;
        if (OUT_BF16) ((u16*)Cv)[idx] = f2bf(val);
        else          ((float*)Cv)[idx] = val;
      }
    }
  }
}

// In-place causal row softmax over bf16 scores (reads only j<=i chunks; writes
// full row with zeros above the diagonal so PV can read whole tiles).
__global__ __launch_bounds__(256)
void softmax_causal_bf16(u16* __restrict__ Pp, int n, long stride)
{
  const int i = blockIdx.x;
  u16* row = Pp + (long)blockIdx.y * stride + (long)i * n;
  const int t = threadIdx.x;
  const int lane = t & 63, wid = t >> 6;
  const int jb = t * 8;

  float v[8];
  const bool any = (jb <= i);
  if (any) {
    short8 sv = *(const short8*)(row + jb);
#pragma unroll
    for (int e = 0; e < 8; ++e) v[e] = bf2f((u16)sv[e]);
  } else {
#pragma unroll
    for (int e = 0; e < 8; ++e) v[e] = 0.0f;
  }

  float mx = -3.0e38f;
#pragma unroll
  for (int e = 0; e < 8; ++e) if (any && jb + e <= i) mx = fmaxf(mx, v[e]);
#pragma unroll
  for (int off = 32; off > 0; off >>= 1) mx = fmaxf(mx, __shfl_xor(mx, off));
  __shared__ float red[8];
  if (lane == 0) red[wid] = mx;
  __syncthreads();
  mx = fmaxf(fmaxf(red[0], red[1]), fmaxf(red[2], red[3]));

  float s = 0.0f;
#pragma unroll
  for (int e = 0; e < 8; ++e) {
    float p = (any && jb + e <= i) ? __expf(v[e] - mx) : 0.0f;
    v[e] = p; s += p;
  }
#pragma unroll
  for (int off = 32; off > 0; off >>= 1) s += __shfl_xor(s, off);
  if (lane == 0) red[4 + wid] = s;
  __syncthreads();
  s = red[4] + red[5] + red[6] + red[7];
  const float inv = 1.0f / s;

  short8 o;
#pragma unroll
  for (int e = 0; e < 8; ++e) o[e] = (short)f2bf(v[e] * inv);
  *(short8*)(row + jb) = o;
}

// All three weight transposes in one dispatch: z=0 Wq->WqkT[0:1024),
// z=1 Wk->WqkT[1024:2048), z=2 Wv->WvT. fp32 -> bf16 transposed.
__global__ __launch_bounds__(256)
void transpose_conv3(const float* __restrict__ Wq, const float* __restrict__ Wk,
                     const float* __restrict__ Wv, u16* __restrict__ WqkT,
                     u16* __restrict__ WvT, int dim)
{
  const float* W;
  u16* WT;
  if (blockIdx.z == 0)      { W = Wq; WT = WqkT; }
  else if (blockIdx.z == 1) { W = Wk; WT = WqkT + (long)dim * dim; }
  else                      { W = Wv; WT = WvT; }

  __shared__ float tile[32][33];
  const int tx = threadIdx.x & 31;
  const int ty = threadIdx.x >> 5;
  const int c0 = blockIdx.x * 32;
  const int r0 = blockIdx.y * 32;
#pragma unroll
  for (int i = 0; i < 4; ++i)
    tile[ty + 8 * i][tx] = W[(long)(r0 + ty + 8 * i) * dim + c0 + tx];
  __syncthreads();
#pragma unroll
  for (int i = 0; i < 4; ++i)
    WT[(long)(c0 + ty + 8 * i) * dim + r0 + tx] = f2bf(tile[tx][ty + 8 * i]);
}

__global__ __launch_bounds__(256)
void conv_bf16(const float* __restrict__ X, u16* __restrict__ Xb, long n8)
{
  const long i = (long)blockIdx.x * 256 + threadIdx.x;
  if (i >= n8) return;
  const float4* s = (const float4*)X + i * 2;
  float4 a = s[0], b = s[1];
  short8 o;
  o[0] = (short)f2bf(a.x); o[1] = (short)f2bf(a.y);
  o[2] = (short)f2bf(a.z); o[3] = (short)f2bf(a.w);
  o[4] = (short)f2bf(b.x); o[5] = (short)f2bf(b.y);
  o[6] = (short)f2bf(b.z); o[7] = (short)f2bf(b.w);
  ((short8*)Xb)[i] = o;
}

// Pack bq|bk into one contiguous bias vector for the fused q/k GEMM.
__global__ __launch_bounds__(256)
void pack_bias2(const float* __restrict__ b0, const float* __restrict__ b1,
                float* __restrict__ dst, int n)
{
  const int i = blockIdx.x * 256 + threadIdx.x;
  if (i < n) dst[i] = b0[i];
  else if (i < 2 * n) dst[i] = b1[i - n];
}

extern "C" void kernel_launch(void* const* d_in, const int* in_sizes, int n_in,
                              void* d_out, int out_size, void* d_ws, size_t ws_size,
                              hipStream_t stream)
{
  const int Bb = 8, S = 2048, Dd = 1024, Od = 1024;
  const int M = Bb * S;  // 16384

  const float* x  = (const float*)d_in[0];
  const float* Wq = (const float*)d_in[1];
  const float* bq = (const float*)d_in[2];
  const float* Wk = (const float*)d_in[3];
  const float* bk = (const float*)d_in[4];
  const float* Wv = (const float*)d_in[5];
  const float* bv = (const float*)d_in[6];
  float* out = (float*)d_out;

  char* ws = (char*)d_ws;
  u16* xb   = (u16*)(ws);                 // x bf16 [16384][1024], 32MB (dead after projections)
  u16* qk   = (u16*)(ws + 33554432L);     // fused q|k [16384][2048] bf16, 64MB
  u16* vT   = (u16*)(ws + 100663296L);    // v^T [1024][16384] bf16, 32MB
  u16* WqkT = (u16*)(ws + 134217728L);    // packed [2048][1024] bf16, 4MB
  u16* WvT  = (u16*)(ws + 138412032L);    // [1024][1024] bf16, 2MB
  float* bqk = (float*)(ws + 140509184L); // packed [2048] fp32, 8KB
  const size_t attn_base = 140517376UL;

  conv_bf16<<<dim3(8192), dim3(256), 0, stream>>>(x, xb, (long)M * Dd / 8);
  transpose_conv3<<<dim3(32, 32, 3), dim3(256), 0, stream>>>(Wq, Wk, Wv, WqkT, WvT, Dd);
  pack_bias2<<<dim3(8), dim3(256), 0, stream>>>(bq, bk, bqk, Od);

  // Fused q|k projection (deep-pipelined 256^2): C[16384][2048].
  gemm256<1, true, false, false, 2><<<dim3(2 * Od / 256, M / 256), dim3(512), 0, stream>>>(
      xb, Dd, 0L, WqkT, Dd, 0L, qk, 2 * Od, 0L, bqk, 1.0f, Dd);
  // v^T (deep-pipelined 256^2): vT[d][m] = WvT[d][:] . xb[m][:] + bv[d].
  gemm256<2, true, false, false, 1><<<dim3(M / 256, Od / 256), dim3(512), 0, stream>>>(
      WvT, Dd, 0L, xb, Dd, 0L, vT, M, 0L, bv, 1.0f, Dd);

  const u16* qb = qk;            // lda = 2048
  const u16* kb = qk + Od;       // lda = 2048
  const int ldqk = 2 * Od;
  const long strideQK = (long)S * ldqk;
  const long sS = (long)S * S;

  // Score buffer: tail region if 8 batches fit; else reuse dead xb (4 fit).
  u16* scores;
  int g;
  if (ws_size >= attn_base + 8UL * (size_t)sS * sizeof(u16)) {
    scores = (u16*)(ws + attn_base);
    g = 8;
  } else {
    scores = xb;
    g = 4;
  }

  const float sc = 0.03125f;  // 1/sqrt(1024)
  for (int b0 = 0; b0 < Bb; b0 += g) {
    const int gz = (b0 + g <= Bb) ? g : (Bb - b0);
    // scores (deep-pipelined 256^2, causal tile-skip, bf16 out)
    gemm256<0, true, true, false, 0><<<dim3(S / 256, S / 256, gz), dim3(512), 0, stream>>>(
        qb + (long)b0 * strideQK, ldqk, strideQK,
        kb + (long)b0 * strideQK, ldqk, strideQK,
        scores, S, sS, nullptr, sc, Od);
    // in-place softmax -> bf16 probs (zeros above diagonal)
    softmax_causal_bf16<<<dim3(S, gz), dim3(256), 0, stream>>>(scores, S, sS);
    // out = probs @ v (deep-pipelined 256^2, fp32 out, causal K-limit).
    // Grid 4x8xz = 256 blocks at z=8: exactly 1 block/CU, makespan = K=2048 block.
    gemm256<0, false, false, true, 0><<<dim3(Od / 256, S / 256, gz), dim3(512), 0, stream>>>(
        scores, S, sS, vT + (long)b0 * S, M, (long)S,
        out + (long)b0 * S * Od, Od, (long)S * Od, nullptr, 1.0f, S);
  }
}